// Round 6
// baseline (224.079 us; speedup 1.0000x reference)
//
#include <hip/hip_runtime.h>
#include <math.h>

// ---------- problem constants ----------
#define BATCH   16
#define LIN     320000
#define LP      322048          // LIN + 2048 (reflect pad 1024 each side)
#define HLP     (LP/2)          // 161024 : even/odd de-interleaved length
#define TFR     626             // frames per batch
#define MTOT    (BATCH*TFR)     // 10016
#define KD2     1024            // radix-2 GEMM K (length-1024 sub-DFTs)
#define KOUT    1025
#define IMAG_OFF ((long)MTOT*KOUT)   // 10266400

// radix-2 packed columns: C = g*64 + q*16 + u ; k' = g*16+u (0..575, valid<=512)
// q: 0=E_r 1=E_i 2=O_r 3=O_i.  S[k'] = E + tw*O ; S[1024-k'] = conj(E - tw*O)
#define MT 79                   // m-tiles (128 rows)
#define NT 9                    // k'-tiles (64 k' = 256 packed cols)
// band-per-XCD mapping: XCD j owns mt in [10j, 10j+10) (last band 9 + 9 dead wgs)
#define BAND 10
#define GEMM_GRID (8*BAND*NT)   // 720

#define XP_BLOCKS   ((BATCH*LP)/2048)   // 2516 (8 elems/thread)
#define W2_BLOCKS   (36*16)             // 576: 36 k'-groups x 16 j-blocks

typedef __attribute__((ext_vector_type(8))) short short8;
typedef __attribute__((ext_vector_type(4))) short short4v;
typedef __attribute__((ext_vector_type(4))) float float4v;
typedef unsigned short ushort_t;

#define PI_OVER_1024 0.0030679615757712823f

static __device__ __forceinline__ ushort_t f32_to_bf16(float f) {
    union { float f; unsigned u; } un; un.f = f;
    unsigned r = un.u + 0x7fffu + ((un.u >> 16) & 1u);   // RNE
    return (ushort_t)(r >> 16);
}

static __device__ __forceinline__ void async_copy16(const void* g, void* l) {
    __builtin_amdgcn_global_load_lds(
        (const __attribute__((address_space(1))) void*)g,
        (__attribute__((address_space(3))) void*)l, 16, 0, 0);
}

// ---------- fused prep: xp_e/xp_o build | packed radix-2 weight build ----------
__global__ void prep(const float* __restrict__ x,
                     const float* __restrict__ wr,
                     const float* __restrict__ wi,
                     ushort_t* __restrict__ xpe,
                     ushort_t* __restrict__ xpo,
                     ushort_t* __restrict__ wbt) {
    __shared__ float sR[128][17];
    __shared__ float sI[128][17];
    const int blk = blockIdx.x;

    if (blk < XP_BLOCKS) {
        // reflect-pad fp32 x -> bf16, de-interleaved even/odd streams
        int i0 = blk * 2048 + threadIdx.x * 8;   // multiple of 8; never spans batch
        int b  = i0 / LP;
        int p0 = i0 - b * LP;                    // even
        float v[8];
        if (p0 >= 1024 && p0 + 8 <= 1024 + LIN) {        // interior fast path
            const float* src = x + b * LIN + (p0 - 1024);
            float4v u0 = *(const float4v*)src;
            float4v u1 = *(const float4v*)(src + 4);
#pragma unroll
            for (int e = 0; e < 4; ++e) { v[e] = u0[e]; v[4+e] = u1[e]; }
        } else {
#pragma unroll
            for (int e = 0; e < 8; ++e) {
                int i = i0 + e;
                int bb = i / LP;
                int j = (i - bb * LP) - 1024;
                if (j < 0) j = -j;
                else if (j >= LIN) j = 2 * LIN - 2 - j;
                v[e] = x[bb * LIN + j];
            }
        }
        short4v ve, vo;
#pragma unroll
        for (int e = 0; e < 4; ++e) {
            ve[e] = (short)f32_to_bf16(v[2*e]);
            vo[e] = (short)f32_to_bf16(v[2*e+1]);
        }
        int he = b * HLP + (p0 >> 1);
        *(short4v*)(xpe + he) = ve;
        *(short4v*)(xpo + he) = vo;
    } else {
        // packed radix-2 weight: row C = gk*64 + q*16 + u, cols j (K=1024)
        // WE_r[j,k']=wr[2j,k']  WE_i=wi[2j,k']
        // WO_r[j,k']=cosd*wr[2j+1,k']-sind*wi[2j+1,k']   (d = pi*k'/1024)
        // WO_i[j,k']=cosd*wi[2j+1,k']+sind*wr[2j+1,k']
        int w  = blk - XP_BLOCKS;     // 0..575
        int gk = w >> 4;              // k'-group 0..35
        int j0 = (w & 15) * 64;       // j-block
        int n0 = j0 * 2;              // source rows n0..n0+127 (<=2047)
        int kb = gk * 16;             // k' base (<=560; reads <=575 < 1025 OK)
        {
            int c  = threadIdx.x & 15;
            int rs = threadIdx.x >> 4;
#pragma unroll
            for (int it = 0; it < 8; ++it) {
                int row = rs + it * 16;
                long src = (long)(n0 + row) * KOUT + kb + c;
                sR[row][c] = wr[src];
                sI[row][c] = wi[src];
            }
        }
        __syncthreads();
        int q  = threadIdx.x >> 6;    // wave = quantity (uniform branch)
        int jj = threadIdx.x & 63;
#pragma unroll
        for (int u = 0; u < 16; ++u) {
            int kp = kb + u;
            float val;
            if (q == 0)      val = sR[2*jj][u];
            else if (q == 1) val = sI[2*jj][u];
            else {
                float r1 = sR[2*jj+1][u], i1 = sI[2*jj+1][u];
                float a  = (float)kp * PI_OVER_1024;
                float sd = __sinf(a), cd = __cosf(a);
                val = (q == 2) ? (cd * r1 - sd * i1) : (cd * i1 + sd * r1);
            }
            if (kp > 512) val = 0.f;                 // pad cols -> exact zero acc
            wbt[(long)(gk * 64 + q * 16 + u) * KD2 + j0 + jj] = f32_to_bf16(val);
        }
    }
}

// ---------- main GEMM: radix-2, 128m x 256c tile, BK=64, 4 waves x (64x128) ----
// Wave tile 64x128 (4mi x 8ni = two k'-groups): ds_read per MFMA 0.75->0.5 KB,
// LDS-read floor 42->31 us. 256 threads, 2 blocks/CU (64 KB LDS).
// Proven pieces kept bit-identical: 8-granule XOR swizzle (0 conflicts),
// band-per-XCD map (FETCH at demand minimum), single-buffer 2-barrier loop.
__global__ __launch_bounds__(256) void stft_gemm(const ushort_t* __restrict__ xpe,
                                                 const ushort_t* __restrict__ xpo,
                                                 const ushort_t* __restrict__ wbt,
                                                 float* __restrict__ out) {
    __shared__ __align__(16) ushort_t Ae[128 * 64];   // 16 KB
    __shared__ __align__(16) ushort_t Ao[128 * 64];   // 16 KB
    __shared__ __align__(16) ushort_t Bs[256 * 64];   // 32 KB

    const int tid = threadIdx.x;
    const int f   = blockIdx.x;            // 0..719
    const int xcd = f & 7;                 // HW round-robins blocks across XCDs
    const int ii  = f >> 3;                // 0..89
    const int mt  = xcd * BAND + (ii % BAND);
    const int nt  = ii / BAND;             // 0..8
    if (mt >= MT) return;                  // 9 dead wgs (whole block exits)
    const int m0  = mt * 128;
    const int c0  = nt * 256;              // packed col base (<=2048)

    // staging source offsets: slot s -> row=s>>3, phys granule=s&7,
    // logical granule g=(s&7)^(row&7); source k-offset = g*8
    int baseA[4], baseB[8];
#pragma unroll
    for (int j = 0; j < 4; ++j) {
        int slot = j * 256 + tid;          // 0..1023 (A: 128 rows x 8 granules)
        int row  = slot >> 3;
        int g    = (slot & 7) ^ (row & 7);
        int m = m0 + row; if (m > MTOT - 1) m = MTOT - 1;   // clamp; stores guarded
        int b = m / TFR;
        int t = m - b * TFR;
        baseA[j] = b * HLP + t * 256 + g * 8;   // frame step = 256 in e/o streams
    }
#pragma unroll
    for (int j = 0; j < 8; ++j) {
        int slot = j * 256 + tid;          // 0..2047 (B: 256 rows x 8 granules)
        int row  = slot >> 3;
        int g    = (slot & 7) ^ (row & 7);
        baseB[j] = (c0 + row) * KD2 + g * 8;    // c0+row < 2304 always
    }

    const int wave = tid >> 6;             // 0..3
    const int lane = tid & 63;
    const int wm = (wave >> 1) * 64;       // 2 m-rows of waves
    const int wn = (wave & 1) * 128;       // 2 n-cols of waves (128 packed cols)
    const int lm = lane & 15;
    const int quad = lane >> 4;

    float4v acc[4][8];
#pragma unroll
    for (int mi = 0; mi < 4; ++mi)
#pragma unroll
        for (int ni = 0; ni < 8; ++ni)
            acc[mi][ni] = (float4v){0.f, 0.f, 0.f, 0.f};

    for (int k0 = 0; k0 < KD2; k0 += 64) {
        __syncthreads();                          // prior ds_reads done
#pragma unroll
        for (int j = 0; j < 4; ++j) {
            int ds = (j * 256 + tid) * 16;
            async_copy16(xpe + baseA[j] + k0, (char*)Ae + ds);
            async_copy16(xpo + baseA[j] + k0, (char*)Ao + ds);
        }
#pragma unroll
        for (int j = 0; j < 8; ++j)
            async_copy16(wbt + baseB[j] + k0, (char*)Bs + (j * 256 + tid) * 16);
        __syncthreads();                          // drains vmcnt

#pragma unroll
        for (int kk = 0; kk < 2; ++kk) {
            short8 ae[4], ao[4], bfr[8];
#pragma unroll
            for (int mi = 0; mi < 4; ++mi) {
                int row = wm + mi * 16 + lm;
                int pg  = (kk * 4 + quad) ^ (row & 7);
                ae[mi] = *(const short8*)&Ae[row * 64 + pg * 8];
                ao[mi] = *(const short8*)&Ao[row * 64 + pg * 8];
            }
#pragma unroll
            for (int ni = 0; ni < 8; ++ni) {
                int row = wn + ni * 16 + lm;
                int pg  = (kk * 4 + quad) ^ (row & 7);
                bfr[ni] = *(const short8*)&Bs[row * 64 + pg * 8];
            }
#pragma unroll
            for (int mi = 0; mi < 4; ++mi)
#pragma unroll
                for (int ni = 0; ni < 8; ++ni)
                    acc[mi][ni] = __builtin_amdgcn_mfma_f32_16x16x32_bf16(
                        ((ni & 3) < 2) ? ae[mi] : ao[mi], bfr[ni], acc[mi][ni], 0, 0, 0);
        }
    }

    // epilogue: lane holds E_r,E_i,O_r,O_i for TWO k' (groups h=0,1) in
    // acc[mi][h*4+q][rg].  butterfly: P = tw*O, tw = e^{-i pi k'/1024};
    //   out[k']      = (E_r+P_r, E_i+P_i)
    //   out[1024-k'] = (E_r-P_r, -E_i+P_i)   (k'=512: O-imag weights exactly 0 -> identical)
    const int grp0 = (c0 + wn) >> 6;
#pragma unroll
    for (int h = 0; h < 2; ++h) {
        const int kp = (grp0 + h) * 16 + lm;       // this lane's k' for group h
        if (kp <= 512) {
            float a  = (float)kp * PI_OVER_1024;
            float sd = __sinf(a), cd = __cosf(a);  // tw = cd - i*sd
#pragma unroll
            for (int mi = 0; mi < 4; ++mi) {
#pragma unroll
                for (int rg = 0; rg < 4; ++rg) {
                    int m = m0 + wm + mi * 16 + quad * 4 + rg;
                    if (m < MTOT) {
                        float Er = acc[mi][h*4+0][rg], Ei = acc[mi][h*4+1][rg];
                        float Or = acc[mi][h*4+2][rg], Oi = acc[mi][h*4+3][rg];
                        float Pr = cd * Or + sd * Oi;
                        float Pi = cd * Oi - sd * Or;
                        long rb = (long)m * KOUT;
                        out[rb + kp]                   = Er + Pr;
                        out[IMAG_OFF + rb + kp]        = Ei + Pi;
                        out[rb + 1024 - kp]            = Er - Pr;
                        out[IMAG_OFF + rb + 1024 - kp] = -Ei + Pi;
                    }
                }
            }
        }
    }
}

extern "C" void kernel_launch(void* const* d_in, const int* in_sizes, int n_in,
                              void* d_out, int out_size, void* d_ws, size_t ws_size,
                              hipStream_t stream) {
    const float* x  = (const float*)d_in[0];     // fp32 (16, 320000)
    const float* wr = (const float*)d_in[1];     // fp32 (2048, 1025)
    const float* wi = (const float*)d_in[2];     // fp32 (2048, 1025)
    float* out = (float*)d_out;                  // fp32, 2*16*626*1025

    ushort_t* xpe = (ushort_t*)d_ws;             // 16*161024 bf16 = 5.15 MB
    ushort_t* xpo = xpe + BATCH * HLP;           // 5.15 MB
    ushort_t* wbt = xpo + BATCH * HLP;           // 2304*1024 bf16 = 4.72 MB

    prep<<<XP_BLOCKS + W2_BLOCKS, 256, 0, stream>>>(x, wr, wi, xpe, xpo, wbt);
    stft_gemm<<<GEMM_GRID, 256, 0, stream>>>(xpe, xpo, wbt, out);   // band-mapped
}

// Round 7
// 176.115 us; speedup vs baseline: 1.2723x; 1.2723x over previous
//
#include <hip/hip_runtime.h>
#include <math.h>

// ---------- problem constants ----------
#define BATCH   16
#define LIN     320000
#define LP      322048          // LIN + 2048 (reflect pad 1024 each side)
#define HLP     (LP/2)          // 161024 : even/odd de-interleaved length
#define TFR     626             // frames per batch
#define MTOT    (BATCH*TFR)     // 10016
#define KD2     1024            // radix-2 GEMM K (length-1024 sub-DFTs)
#define KOUT    1025
#define IMAG_OFF ((long)MTOT*KOUT)   // 10266400

// radix-2 packed columns: C = g*64 + q*16 + u ; k' = g*16+u (0..575, valid<=512)
// q: 0=E_r 1=E_i 2=O_r 3=O_i.  S[k'] = E + tw*O ; S[1024-k'] = conj(E - tw*O)
#define MT 79                   // m-tiles (128 rows)
#define NT 9                    // k'-tiles (64 k' = 256 packed cols)
#define BAND 10
#define GEMM_GRID (8*BAND*NT)   // 720

#define XP_BLOCKS   ((BATCH*LP)/2048)   // 2516 (8 elems/thread)
#define W2_BLOCKS   (36*16)             // 576: 36 k'-groups x 16 j-blocks

typedef __attribute__((ext_vector_type(8))) short short8;
typedef __attribute__((ext_vector_type(4))) short short4v;
typedef __attribute__((ext_vector_type(4))) float float4v;
typedef unsigned short ushort_t;

#define PI_OVER_1024 0.0030679615757712823f

static __device__ __forceinline__ ushort_t f32_to_bf16(float f) {
    union { float f; unsigned u; } un; un.f = f;
    unsigned r = un.u + 0x7fffu + ((un.u >> 16) & 1u);   // RNE
    return (ushort_t)(r >> 16);
}

static __device__ __forceinline__ void async_copy16(const void* g, void* l) {
    __builtin_amdgcn_global_load_lds(
        (const __attribute__((address_space(1))) void*)g,
        (__attribute__((address_space(3))) void*)l, 16, 0, 0);
}

// ---------- fused prep: xp_e/xp_o build | packed radix-2 weight build ----------
__global__ void prep(const float* __restrict__ x,
                     const float* __restrict__ wr,
                     const float* __restrict__ wi,
                     ushort_t* __restrict__ xpe,
                     ushort_t* __restrict__ xpo,
                     ushort_t* __restrict__ wbt) {
    __shared__ float sR[128][17];
    __shared__ float sI[128][17];
    const int blk = blockIdx.x;

    if (blk < XP_BLOCKS) {
        int i0 = blk * 2048 + threadIdx.x * 8;   // multiple of 8; never spans batch
        int b  = i0 / LP;
        int p0 = i0 - b * LP;                    // even
        float v[8];
        if (p0 >= 1024 && p0 + 8 <= 1024 + LIN) {        // interior fast path
            const float* src = x + b * LIN + (p0 - 1024);
            float4v u0 = *(const float4v*)src;
            float4v u1 = *(const float4v*)(src + 4);
#pragma unroll
            for (int e = 0; e < 4; ++e) { v[e] = u0[e]; v[4+e] = u1[e]; }
        } else {
#pragma unroll
            for (int e = 0; e < 8; ++e) {
                int i = i0 + e;
                int bb = i / LP;
                int j = (i - bb * LP) - 1024;
                if (j < 0) j = -j;
                else if (j >= LIN) j = 2 * LIN - 2 - j;
                v[e] = x[bb * LIN + j];
            }
        }
        short4v ve, vo;
#pragma unroll
        for (int e = 0; e < 4; ++e) {
            ve[e] = (short)f32_to_bf16(v[2*e]);
            vo[e] = (short)f32_to_bf16(v[2*e+1]);
        }
        int he = b * HLP + (p0 >> 1);
        *(short4v*)(xpe + he) = ve;
        *(short4v*)(xpo + he) = vo;
    } else {
        int w  = blk - XP_BLOCKS;     // 0..575
        int gk = w >> 4;              // k'-group 0..35
        int j0 = (w & 15) * 64;       // j-block
        int n0 = j0 * 2;              // source rows n0..n0+127 (<=2047)
        int kb = gk * 16;             // k' base (<=560; reads <=575 < 1025 OK)
        {
            int c  = threadIdx.x & 15;
            int rs = threadIdx.x >> 4;
#pragma unroll
            for (int it = 0; it < 8; ++it) {
                int row = rs + it * 16;
                long src = (long)(n0 + row) * KOUT + kb + c;
                sR[row][c] = wr[src];
                sI[row][c] = wi[src];
            }
        }
        __syncthreads();
        int q  = threadIdx.x >> 6;    // wave = quantity (uniform branch)
        int jj = threadIdx.x & 63;
#pragma unroll
        for (int u = 0; u < 16; ++u) {
            int kp = kb + u;
            float val;
            if (q == 0)      val = sR[2*jj][u];
            else if (q == 1) val = sI[2*jj][u];
            else {
                float r1 = sR[2*jj+1][u], i1 = sI[2*jj+1][u];
                float a  = (float)kp * PI_OVER_1024;
                float sd = __sinf(a), cd = __cosf(a);
                val = (q == 2) ? (cd * r1 - sd * i1) : (cd * i1 + sd * r1);
            }
            if (kp > 512) val = 0.f;                 // pad cols -> exact zero acc
            wbt[(long)(gk * 64 + q * 16 + u) * KD2 + j0 + jj] = f32_to_bf16(val);
        }
    }
}

// ---------- main GEMM: radix-2, 128m x 256c, BK=64, counted-vmcnt phase pipeline --
// R5 geometry (8-granule XOR swizzle = 0 conflicts; band-per-XCD map = demand-min
// FETCH) with the K-loop replaced by a T3+T4+T5 pipeline:
//   dbuf 2 x 64 KB LDS (1 block/CU); 4 phases/K-tile, each {2 stage issues,
//   ds_read subtile, s_barrier, setprio(1) 8xMFMA setprio(0), s_barrier};
//   ONE s_waitcnt vmcnt(2) per K-tile at the buffer handoff (never 0 in-loop).
__global__ __launch_bounds__(512, 2) void stft_gemm(const ushort_t* __restrict__ xpe,
                                                    const ushort_t* __restrict__ xpo,
                                                    const ushort_t* __restrict__ wbt,
                                                    float* __restrict__ out) {
    // per buffer (32768 ushort): Ae [0,8192) | Ao [8192,16384) | B [16384,32768)
    __shared__ __align__(16) ushort_t LD[2][32768];   // 128 KB total

    const int tid = threadIdx.x;
    const int f   = blockIdx.x;            // 0..719
    const int xcd = f & 7;
    const int ii  = f >> 3;                // 0..89
    const int mt  = xcd * BAND + (ii % BAND);
    const int nt  = ii / BAND;             // 0..8
    if (mt >= MT) return;                  // 9 dead wgs (whole block exits pre-barrier)
    const int m0  = mt * 128;
    const int c0  = nt * 256;              // packed col base (<=2048)

    // staging source offsets: slot s -> row=s>>3, phys granule=s&7,
    // logical granule g=(s&7)^(row&7); source k-offset = g*8
    int baseA[2], baseB[4];
#pragma unroll
    for (int j = 0; j < 2; ++j) {
        int slot = j * 512 + tid;          // 0..1023 (A: 128 rows x 8 granules)
        int row  = slot >> 3;
        int g    = (slot & 7) ^ (row & 7);
        int m = m0 + row; if (m > MTOT - 1) m = MTOT - 1;   // clamp; stores guarded
        int b = m / TFR;
        int t = m - b * TFR;
        baseA[j] = b * HLP + t * 256 + g * 8;   // frame step = 256 in e/o streams
    }
#pragma unroll
    for (int j = 0; j < 4; ++j) {
        int slot = j * 512 + tid;          // 0..2047 (B: 256 rows x 8 granules)
        int row  = slot >> 3;
        int g    = (slot & 7) ^ (row & 7);
        baseB[j] = (c0 + row) * KD2 + g * 8;    // c0+row < 2304 always
    }
    const int dsA0 = tid * 16;                    // byte offsets within regions
    const int dsA1 = (512 + tid) * 16;
    const int dsB0 = tid * 16,        dsB1 = (512 + tid) * 16;
    const int dsB2 = (1024 + tid) * 16, dsB3 = (1536 + tid) * 16;

    const int wave = tid >> 6;             // 0..7
    const int lane = tid & 63;
    const int wm = (wave >> 2) * 64;       // 2 m-rows of waves
    const int wn = (wave & 3) * 64;        // 4 n-cols of waves
    const int lm = lane & 15;
    const int quad = lane >> 4;

    float4v acc[4][4];
#pragma unroll
    for (int mi = 0; mi < 4; ++mi)
#pragma unroll
        for (int ni = 0; ni < 4; ++ni)
            acc[mi][ni] = (float4v){0.f, 0.f, 0.f, 0.f};

    // prologue: stage tile 0 into buf0 (8 loads; drained by the t=0 vmcnt(2))
    {
        char* D = (char*)&LD[0][0];
        async_copy16(xpe + baseA[0], D + dsA0);
        async_copy16(xpo + baseA[0], D + 16384 + dsA0);
        async_copy16(xpe + baseA[1], D + dsA1);
        async_copy16(xpo + baseA[1], D + 16384 + dsA1);
        async_copy16(wbt + baseB[0], D + 32768 + dsB0);
        async_copy16(wbt + baseB[1], D + 32768 + dsB1);
        async_copy16(wbt + baseB[2], D + 32768 + dsB2);
        async_copy16(wbt + baseB[3], D + 32768 + dsB3);
    }

#define RD_A(mi_, kk_) { int row_ = wm + (mi_)*16 + lm;                          \
        int pg_ = ((kk_)*4 + quad) ^ (row_ & 7);                                 \
        ae[mi_] = *(const short8*)&L[row_*64 + pg_*8];                           \
        ao[mi_] = *(const short8*)&L[8192 + row_*64 + pg_*8]; }
#define RD_B(ni_, kk_) { int row_ = wn + (ni_)*16 + lm;                          \
        int pg_ = ((kk_)*4 + quad) ^ (row_ & 7);                                 \
        bfr[ni_] = *(const short8*)&L[16384 + row_*64 + pg_*8]; }
#define MFMA_PAIR(miA, miB)                                                      \
        __builtin_amdgcn_s_setprio(1);                                           \
        _Pragma("unroll")                                                        \
        for (int ni = 0; ni < 4; ++ni) {                                         \
            acc[miA][ni] = __builtin_amdgcn_mfma_f32_16x16x32_bf16(              \
                (ni < 2) ? ae[miA] : ao[miA], bfr[ni], acc[miA][ni], 0, 0, 0);   \
            acc[miB][ni] = __builtin_amdgcn_mfma_f32_16x16x32_bf16(              \
                (ni < 2) ? ae[miB] : ao[miB], bfr[ni], acc[miB][ni], 0, 0, 0);   \
        }                                                                        \
        __builtin_amdgcn_s_setprio(0);

    for (int t = 0; t < 16; ++t) {
        const ushort_t* L = &LD[t & 1][0];
        char* DN = (char*)&LD[(t & 1) ^ 1][0];
        const int k0n = (t < 15 ? t + 1 : t) * 64;   // t=15: harmless restage (dead buf)

        short8 ae[4], ao[4], bfr[4];

        // ---- phase 1: stage A(j0) | vmcnt(2) buffer handoff | kk0 mi{0,1} ----
        async_copy16(xpe + baseA[0] + k0n, DN + dsA0);
        async_copy16(xpo + baseA[0] + k0n, DN + 16384 + dsA0);
        asm volatile("s_waitcnt vmcnt(2)" ::: "memory");   // prev tile's 8 landed
        __builtin_amdgcn_s_barrier();                      // all waves' loads landed
        RD_A(0, 0) RD_A(1, 0)
        RD_B(0, 0) RD_B(1, 0) RD_B(2, 0) RD_B(3, 0)
        __builtin_amdgcn_s_barrier();
        MFMA_PAIR(0, 1)
        __builtin_amdgcn_s_barrier();

        // ---- phase 2: kk0 mi{2,3} | stage A(j1) ----
        RD_A(2, 0) RD_A(3, 0)
        async_copy16(xpe + baseA[1] + k0n, DN + dsA1);
        async_copy16(xpo + baseA[1] + k0n, DN + 16384 + dsA1);
        __builtin_amdgcn_s_barrier();
        MFMA_PAIR(2, 3)
        __builtin_amdgcn_s_barrier();

        // ---- phase 3: kk1 mi{0,1} | stage B(j0,j1) ----
        RD_A(0, 1) RD_A(1, 1)
        RD_B(0, 1) RD_B(1, 1) RD_B(2, 1) RD_B(3, 1)
        async_copy16(wbt + baseB[0] + k0n, DN + 32768 + dsB0);
        async_copy16(wbt + baseB[1] + k0n, DN + 32768 + dsB1);
        __builtin_amdgcn_s_barrier();
        MFMA_PAIR(0, 1)
        __builtin_amdgcn_s_barrier();

        // ---- phase 4: kk1 mi{2,3} | stage B(j2,j3) ----
        RD_A(2, 1) RD_A(3, 1)
        async_copy16(wbt + baseB[2] + k0n, DN + 32768 + dsB2);
        async_copy16(wbt + baseB[3] + k0n, DN + 32768 + dsB3);
        __builtin_amdgcn_s_barrier();
        MFMA_PAIR(2, 3)
        __builtin_amdgcn_s_barrier();
    }
#undef RD_A
#undef RD_B
#undef MFMA_PAIR

    // epilogue: lane holds E_r,E_i,O_r,O_i of its k' in acc[mi][0..3][rg].
    // butterfly: P = tw*O, tw = e^{-i pi k'/1024};
    //   out[k']      = (E_r+P_r, E_i+P_i)
    //   out[1024-k'] = (E_r-P_r, -E_i+P_i)   (k'=512: O-imag weights exactly 0 -> identical)
    const int grp = (c0 + wn) >> 6;
    const int kp  = grp * 16 + lm;             // this lane's k'
    if (kp <= 512) {
        float a  = (float)kp * PI_OVER_1024;
        float sd = __sinf(a), cd = __cosf(a);  // tw = cd - i*sd
#pragma unroll
        for (int mi = 0; mi < 4; ++mi) {
#pragma unroll
            for (int rg = 0; rg < 4; ++rg) {
                int m = m0 + wm + mi * 16 + quad * 4 + rg;
                if (m < MTOT) {
                    float Er = acc[mi][0][rg], Ei = acc[mi][1][rg];
                    float Or = acc[mi][2][rg], Oi = acc[mi][3][rg];
                    float Pr = cd * Or + sd * Oi;
                    float Pi = cd * Oi - sd * Or;
                    long rb = (long)m * KOUT;
                    out[rb + kp]                   = Er + Pr;
                    out[IMAG_OFF + rb + kp]        = Ei + Pi;
                    out[rb + 1024 - kp]            = Er - Pr;
                    out[IMAG_OFF + rb + 1024 - kp] = -Ei + Pi;
                }
            }
        }
    }
}

extern "C" void kernel_launch(void* const* d_in, const int* in_sizes, int n_in,
                              void* d_out, int out_size, void* d_ws, size_t ws_size,
                              hipStream_t stream) {
    const float* x  = (const float*)d_in[0];     // fp32 (16, 320000)
    const float* wr = (const float*)d_in[1];     // fp32 (2048, 1025)
    const float* wi = (const float*)d_in[2];     // fp32 (2048, 1025)
    float* out = (float*)d_out;                  // fp32, 2*16*626*1025

    ushort_t* xpe = (ushort_t*)d_ws;             // 16*161024 bf16 = 5.15 MB
    ushort_t* xpo = xpe + BATCH * HLP;           // 5.15 MB
    ushort_t* wbt = xpo + BATCH * HLP;           // 2304*1024 bf16 = 4.72 MB

    prep<<<XP_BLOCKS + W2_BLOCKS, 256, 0, stream>>>(x, wr, wi, xpe, xpo, wbt);
    stft_gemm<<<GEMM_GRID, 512, 0, stream>>>(xpe, xpo, wbt, out);   // band-mapped
}

// Round 8
// 168.913 us; speedup vs baseline: 1.3266x; 1.0426x over previous
//
#include <hip/hip_runtime.h>
#include <math.h>

// ---------- problem constants ----------
#define BATCH   16
#define LIN     320000
#define LP      322048          // LIN + 2048 (reflect pad 1024 each side)
#define HLP     (LP/2)          // 161024 : even/odd de-interleaved length
#define TFR     626             // frames per batch
#define MTOT    (BATCH*TFR)     // 10016
#define KD2     1024            // radix-2 GEMM K (length-1024 sub-DFTs)
#define KOUT    1025
#define IMAG_OFF ((long)MTOT*KOUT)   // 10266400

// radix-2 packed columns: C = g*64 + q*16 + u ; k' = g*16+u (0..575, valid<=512)
// q: 0=E_r 1=E_i 2=O_r 3=O_i.  S[k'] = E + tw*O ; S[1024-k'] = conj(E - tw*O)
#define MT 79                   // m-tiles (128 rows)
#define NT 9                    // k'-tiles (64 k' = 256 packed cols)
#define BAND 10
#define GEMM_GRID (8*BAND*NT)   // 720

#define XP_BLOCKS   ((BATCH*LP)/2048)   // 2516 (8 elems/thread)
#define W2_BLOCKS   (36*16)             // 576: 36 k'-groups x 16 j-blocks

typedef __attribute__((ext_vector_type(8))) short short8;
typedef __attribute__((ext_vector_type(4))) short short4v;
typedef __attribute__((ext_vector_type(4))) float float4v;
typedef unsigned short ushort_t;

#define PI_OVER_1024 0.0030679615757712823f

static __device__ __forceinline__ ushort_t f32_to_bf16(float f) {
    union { float f; unsigned u; } un; un.f = f;
    unsigned r = un.u + 0x7fffu + ((un.u >> 16) & 1u);   // RNE
    return (ushort_t)(r >> 16);
}

static __device__ __forceinline__ void async_copy16(const void* g, void* l) {
    __builtin_amdgcn_global_load_lds(
        (const __attribute__((address_space(1))) void*)g,
        (__attribute__((address_space(3))) void*)l, 16, 0, 0);
}

// ---------- fused prep: xp_e/xp_o build | packed radix-2 weight build ----------
__global__ void prep(const float* __restrict__ x,
                     const float* __restrict__ wr,
                     const float* __restrict__ wi,
                     ushort_t* __restrict__ xpe,
                     ushort_t* __restrict__ xpo,
                     ushort_t* __restrict__ wbt) {
    __shared__ float sR[128][17];
    __shared__ float sI[128][17];
    const int blk = blockIdx.x;

    if (blk < XP_BLOCKS) {
        int i0 = blk * 2048 + threadIdx.x * 8;   // multiple of 8; never spans batch
        int b  = i0 / LP;
        int p0 = i0 - b * LP;                    // even
        float v[8];
        if (p0 >= 1024 && p0 + 8 <= 1024 + LIN) {        // interior fast path
            const float* src = x + b * LIN + (p0 - 1024);
            float4v u0 = *(const float4v*)src;
            float4v u1 = *(const float4v*)(src + 4);
#pragma unroll
            for (int e = 0; e < 4; ++e) { v[e] = u0[e]; v[4+e] = u1[e]; }
        } else {
#pragma unroll
            for (int e = 0; e < 8; ++e) {
                int i = i0 + e;
                int bb = i / LP;
                int j = (i - bb * LP) - 1024;
                if (j < 0) j = -j;
                else if (j >= LIN) j = 2 * LIN - 2 - j;
                v[e] = x[bb * LIN + j];
            }
        }
        short4v ve, vo;
#pragma unroll
        for (int e = 0; e < 4; ++e) {
            ve[e] = (short)f32_to_bf16(v[2*e]);
            vo[e] = (short)f32_to_bf16(v[2*e+1]);
        }
        int he = b * HLP + (p0 >> 1);
        *(short4v*)(xpe + he) = ve;
        *(short4v*)(xpo + he) = vo;
    } else {
        int w  = blk - XP_BLOCKS;     // 0..575
        int gk = w >> 4;              // k'-group 0..35
        int j0 = (w & 15) * 64;       // j-block
        int n0 = j0 * 2;              // source rows n0..n0+127 (<=2047)
        int kb = gk * 16;             // k' base (<=560; reads <=575 < 1025 OK)
        {
            int c  = threadIdx.x & 15;
            int rs = threadIdx.x >> 4;
#pragma unroll
            for (int it = 0; it < 8; ++it) {
                int row = rs + it * 16;
                long src = (long)(n0 + row) * KOUT + kb + c;
                sR[row][c] = wr[src];
                sI[row][c] = wi[src];
            }
        }
        __syncthreads();
        int q  = threadIdx.x >> 6;    // wave = quantity (uniform branch)
        int jj = threadIdx.x & 63;
#pragma unroll
        for (int u = 0; u < 16; ++u) {
            int kp = kb + u;
            float val;
            if (q == 0)      val = sR[2*jj][u];
            else if (q == 1) val = sI[2*jj][u];
            else {
                float r1 = sR[2*jj+1][u], i1 = sI[2*jj+1][u];
                float a  = (float)kp * PI_OVER_1024;
                float sd = __sinf(a), cd = __cosf(a);
                val = (q == 2) ? (cd * r1 - sd * i1) : (cd * i1 + sd * r1);
            }
            if (kp > 512) val = 0.f;                 // pad cols -> exact zero acc
            wbt[(long)(gk * 64 + q * 16 + u) * KD2 + j0 + jj] = f32_to_bf16(val);
        }
    }
}

// ---------- main GEMM: radix-2, 128m x 256c, BK=64, T3-min counted-vmcnt loop ----
// R5 geometry (8-granule XOR swizzle = 0 conflicts; band-per-XCD = demand-min
// FETCH) + dbuf 2x64KB (1 block/CU). Per K-tile: 2 barriers, ONE vmcnt(4)
// (never 0 in-loop), 16-MFMA setprio clusters. Stage loads issued in tile t
// stay in flight across the end barrier, landing during tile t+1's MFMAs.
__global__ __launch_bounds__(512, 2) void stft_gemm(const ushort_t* __restrict__ xpe,
                                                    const ushort_t* __restrict__ xpo,
                                                    const ushort_t* __restrict__ wbt,
                                                    float* __restrict__ out) {
    // per buffer (32768 ushort): Ae [0,8192) | Ao [8192,16384) | B [16384,32768)
    __shared__ __align__(16) ushort_t LD[2][32768];   // 128 KB total

    const int tid = threadIdx.x;
    const int f   = blockIdx.x;            // 0..719
    const int xcd = f & 7;
    const int ii  = f >> 3;                // 0..89
    const int mt  = xcd * BAND + (ii % BAND);
    const int nt  = ii / BAND;             // 0..8
    if (mt >= MT) return;                  // 9 dead wgs (whole block exits pre-barrier)
    const int m0  = mt * 128;
    const int c0  = nt * 256;              // packed col base (<=2048)

    // staging source offsets: slot s -> row=s>>3, phys granule=s&7,
    // logical granule g=(s&7)^(row&7); source k-offset = g*8
    int baseA[2], baseB[4];
#pragma unroll
    for (int j = 0; j < 2; ++j) {
        int slot = j * 512 + tid;          // 0..1023 (A: 128 rows x 8 granules)
        int row  = slot >> 3;
        int g    = (slot & 7) ^ (row & 7);
        int m = m0 + row; if (m > MTOT - 1) m = MTOT - 1;   // clamp; stores guarded
        int b = m / TFR;
        int t = m - b * TFR;
        baseA[j] = b * HLP + t * 256 + g * 8;   // frame step = 256 in e/o streams
    }
#pragma unroll
    for (int j = 0; j < 4; ++j) {
        int slot = j * 512 + tid;          // 0..2047 (B: 256 rows x 8 granules)
        int row  = slot >> 3;
        int g    = (slot & 7) ^ (row & 7);
        baseB[j] = (c0 + row) * KD2 + g * 8;    // c0+row < 2304 always
    }
    const int dsA0 = tid * 16;                    // byte offsets within regions
    const int dsA1 = (512 + tid) * 16;
    const int dsB0 = tid * 16,        dsB1 = (512 + tid) * 16;
    const int dsB2 = (1024 + tid) * 16, dsB3 = (1536 + tid) * 16;

    const int wave = tid >> 6;             // 0..7
    const int lane = tid & 63;
    const int wm = (wave >> 2) * 64;       // 2 m-rows of waves
    const int wn = (wave & 3) * 64;        // 4 n-cols of waves
    const int lm = lane & 15;
    const int quad = lane >> 4;

    float4v acc[4][4];
#pragma unroll
    for (int mi = 0; mi < 4; ++mi)
#pragma unroll
        for (int ni = 0; ni < 4; ++ni)
            acc[mi][ni] = (float4v){0.f, 0.f, 0.f, 0.f};

    // prologue: stage tile 0 into buf0 (8 loads; retired by the t=0 vmcnt(4))
    {
        char* D = (char*)&LD[0][0];
        async_copy16(xpe + baseA[0], D + dsA0);
        async_copy16(xpo + baseA[0], D + 16384 + dsA0);
        async_copy16(xpe + baseA[1], D + dsA1);
        async_copy16(xpo + baseA[1], D + 16384 + dsA1);
        async_copy16(wbt + baseB[0], D + 32768 + dsB0);
        async_copy16(wbt + baseB[1], D + 32768 + dsB1);
        async_copy16(wbt + baseB[2], D + 32768 + dsB2);
        async_copy16(wbt + baseB[3], D + 32768 + dsB3);
    }

#define RD_A(mi_, kk_) { int row_ = wm + (mi_)*16 + lm;                          \
        int pg_ = ((kk_)*4 + quad) ^ (row_ & 7);                                 \
        ae[mi_] = *(const short8*)&L[row_*64 + pg_*8];                           \
        ao[mi_] = *(const short8*)&L[8192 + row_*64 + pg_*8]; }
#define RD_B(ni_, kk_) { int row_ = wn + (ni_)*16 + lm;                          \
        int pg_ = ((kk_)*4 + quad) ^ (row_ & 7);                                 \
        bfr[ni_] = *(const short8*)&L[16384 + row_*64 + pg_*8]; }
#define MFMA16()                                                                 \
        __builtin_amdgcn_s_setprio(1);                                           \
        _Pragma("unroll")                                                        \
        for (int mi = 0; mi < 4; ++mi)                                           \
            _Pragma("unroll")                                                    \
            for (int ni = 0; ni < 4; ++ni)                                       \
                acc[mi][ni] = __builtin_amdgcn_mfma_f32_16x16x32_bf16(           \
                    (ni < 2) ? ae[mi] : ao[mi], bfr[ni], acc[mi][ni], 0, 0, 0);  \
        __builtin_amdgcn_s_setprio(0);

    for (int t = 0; t < 16; ++t) {
        const ushort_t* L = &LD[t & 1][0];
        char* DN = (char*)&LD[(t & 1) ^ 1][0];
        const int k0n = (t < 15 ? t + 1 : t) * 64;   // t=15: harmless restage (dead buf)

        short8 ae[4], ao[4], bfr[4];

        // ---- P0: stage S0(t+1) | vmcnt(4) handoff | kk0: 12 ds_read + 16 MFMA ----
        async_copy16(xpe + baseA[0] + k0n, DN + dsA0);
        async_copy16(xpo + baseA[0] + k0n, DN + 16384 + dsA0);
        async_copy16(wbt + baseB[0] + k0n, DN + 32768 + dsB0);
        async_copy16(wbt + baseB[1] + k0n, DN + 32768 + dsB1);
        asm volatile("s_waitcnt vmcnt(4)" ::: "memory");   // prev tile's 8 landed
        __builtin_amdgcn_s_barrier();                      // all waves' loads landed
        __builtin_amdgcn_sched_barrier(0);                 // no read hoisting (rule 18)
        RD_A(0, 0) RD_A(1, 0) RD_A(2, 0) RD_A(3, 0)
        RD_B(0, 0) RD_B(1, 0) RD_B(2, 0) RD_B(3, 0)
        MFMA16()

        // ---- P1: stage S1(t+1) | kk1: 12 ds_read + 16 MFMA | end barrier ----
        async_copy16(xpe + baseA[1] + k0n, DN + dsA1);
        async_copy16(xpo + baseA[1] + k0n, DN + 16384 + dsA1);
        async_copy16(wbt + baseB[2] + k0n, DN + 32768 + dsB2);
        async_copy16(wbt + baseB[3] + k0n, DN + 32768 + dsB3);
        RD_A(0, 1) RD_A(1, 1) RD_A(2, 1) RD_A(3, 1)
        RD_B(0, 1) RD_B(1, 1) RD_B(2, 1) RD_B(3, 1)
        MFMA16()
        __builtin_amdgcn_sched_barrier(0);                 // reads stay before barrier
        __builtin_amdgcn_s_barrier();                      // WAR: buf safe to restage
    }
#undef RD_A
#undef RD_B
#undef MFMA16

    // drain in-flight restage loads before epilogue (no loads in flight at endpgm)
    asm volatile("s_waitcnt vmcnt(0)" ::: "memory");

    // epilogue: lane holds E_r,E_i,O_r,O_i of its k' in acc[mi][0..3][rg].
    // butterfly: P = tw*O, tw = e^{-i pi k'/1024};
    //   out[k']      = (E_r+P_r, E_i+P_i)
    //   out[1024-k'] = (E_r-P_r, -E_i+P_i)   (k'=512: O-imag weights exactly 0 -> identical)
    const int grp = (c0 + wn) >> 6;
    const int kp  = grp * 16 + lm;             // this lane's k'
    if (kp <= 512) {
        float a  = (float)kp * PI_OVER_1024;
        float sd = __sinf(a), cd = __cosf(a);  // tw = cd - i*sd
#pragma unroll
        for (int mi = 0; mi < 4; ++mi) {
#pragma unroll
            for (int rg = 0; rg < 4; ++rg) {
                int m = m0 + wm + mi * 16 + quad * 4 + rg;
                if (m < MTOT) {
                    float Er = acc[mi][0][rg], Ei = acc[mi][1][rg];
                    float Or = acc[mi][2][rg], Oi = acc[mi][3][rg];
                    float Pr = cd * Or + sd * Oi;
                    float Pi = cd * Oi - sd * Or;
                    long rb = (long)m * KOUT;
                    out[rb + kp]                   = Er + Pr;
                    out[IMAG_OFF + rb + kp]        = Ei + Pi;
                    out[rb + 1024 - kp]            = Er - Pr;
                    out[IMAG_OFF + rb + 1024 - kp] = -Ei + Pi;
                }
            }
        }
    }
}

extern "C" void kernel_launch(void* const* d_in, const int* in_sizes, int n_in,
                              void* d_out, int out_size, void* d_ws, size_t ws_size,
                              hipStream_t stream) {
    const float* x  = (const float*)d_in[0];     // fp32 (16, 320000)
    const float* wr = (const float*)d_in[1];     // fp32 (2048, 1025)
    const float* wi = (const float*)d_in[2];     // fp32 (2048, 1025)
    float* out = (float*)d_out;                  // fp32, 2*16*626*1025

    ushort_t* xpe = (ushort_t*)d_ws;             // 16*161024 bf16 = 5.15 MB
    ushort_t* xpo = xpe + BATCH * HLP;           // 5.15 MB
    ushort_t* wbt = xpo + BATCH * HLP;           // 2304*1024 bf16 = 4.72 MB

    prep<<<XP_BLOCKS + W2_BLOCKS, 256, 0, stream>>>(x, wr, wi, xpe, xpo, wbt);
    stft_gemm<<<GEMM_GRID, 512, 0, stream>>>(xpe, xpo, wbt, out);   // band-mapped
}

// Round 9
// 159.070 us; speedup vs baseline: 1.4087x; 1.0619x over previous
//
#include <hip/hip_runtime.h>
#include <math.h>

// ---------- problem constants ----------
#define BATCH   16
#define LIN     320000
#define LP      322048          // LIN + 2048 (reflect pad 1024 each side)
#define QLP     (LP/4)          // 80512 : 4-stream de-interleaved length per batch
#define SST     (BATCH*QLP)     // 1288192 : per-stream total elems
#define TFR     626             // frames per batch
#define MTOT    (BATCH*TFR)     // 10016
#define KD4     512             // radix-4 GEMM K (length-512 sub-DFTs)
#define KOUT    1025
#define IMAG_OFF ((long)MTOT*KOUT)   // 10266400

// radix-4 packed cols: C = g*128 + q*16 + u ; k' = g*16+u (0..287, valid<=256)
// q = 2r+im: (E0r,E0i,E1r,E1i,E2r,E2i,E3r,E3i), E_r = stream-r sub-DFT.
// S[k] = Sum_r e^{-i pi k r/1024} E_r[k mod 512];  E_r[512-k'] = conj(E_r[k'])
// -> F_r = t_r*E_r (t_r = e^{-i pi r k'/1024}), A_s = Sum_r (-i)^{rs} F_r:
//    S[k']=A0, S[512+k']=A1, S[1024-k']=conj(A2), S[512-k']=conj(A3)
#define MT 79                   // m-tiles (128 rows)
#define NT 9                    // k'-tiles (32 k' = 256 packed cols; 18 groups)
#define BAND 10
#define GEMM_GRID (8*BAND*NT)   // 720

#define XP_BLOCKS   ((BATCH*LP)/2048)   // 2516 (8 elems/thread)
#define W4_BLOCKS   (18*8)              // 144: 18 k'-groups x 8 j-blocks

typedef __attribute__((ext_vector_type(8))) short short8;
typedef __attribute__((ext_vector_type(4))) float float4v;
typedef unsigned short ushort_t;

#define PI_OVER_1024 0.0030679615757712823f

static __device__ __forceinline__ ushort_t f32_to_bf16(float f) {
    union { float f; unsigned u; } un; un.f = f;
    unsigned r = un.u + 0x7fffu + ((un.u >> 16) & 1u);   // RNE
    return (ushort_t)(r >> 16);
}

static __device__ __forceinline__ void async_copy16(const void* g, void* l) {
    __builtin_amdgcn_global_load_lds(
        (const __attribute__((address_space(1))) void*)g,
        (__attribute__((address_space(3))) void*)l, 16, 0, 0);
}

// ---------- fused prep: 4-stream xp build | packed radix-4 weight build ----------
__global__ void prep(const float* __restrict__ x,
                     const float* __restrict__ wr,
                     const float* __restrict__ wi,
                     ushort_t* __restrict__ xs,
                     ushort_t* __restrict__ wbt) {
    __shared__ float sR[256][17];
    __shared__ float sI[256][17];
    const int blk = blockIdx.x;

    if (blk < XP_BLOCKS) {
        // reflect-pad fp32 x -> bf16, de-interleaved into 4 streams (n mod 4)
        int i0 = blk * 2048 + threadIdx.x * 8;   // multiple of 8; never spans batch
        int b  = i0 / LP;
        int p0 = i0 - b * LP;                    // multiple of 8
        float v[8];
        if (p0 >= 1024 && p0 + 8 <= 1024 + LIN) {        // interior fast path
            const float* src = x + b * LIN + (p0 - 1024);
            float4v u0 = *(const float4v*)src;
            float4v u1 = *(const float4v*)(src + 4);
#pragma unroll
            for (int e = 0; e < 4; ++e) { v[e] = u0[e]; v[4+e] = u1[e]; }
        } else {
#pragma unroll
            for (int e = 0; e < 8; ++e) {
                int i = i0 + e;
                int bb = i / LP;
                int j = (i - bb * LP) - 1024;
                if (j < 0) j = -j;
                else if (j >= LIN) j = 2 * LIN - 2 - j;
                v[e] = x[bb * LIN + j];
            }
        }
        int he = b * QLP + (p0 >> 2);            // even -> 4B aligned uint store
#pragma unroll
        for (int r = 0; r < 4; ++r) {
            unsigned lo = f32_to_bf16(v[r]);
            unsigned hi = f32_to_bf16(v[4 + r]);
            *(unsigned*)(xs + r * SST + he) = lo | (hi << 16);
        }
    } else {
        // packed radix-4 weight: row C = gk*128 + q*16 + u, cols j (K=512)
        // q=2r+im, delta = pi*r*k'/1024:
        //   W_re = cosd*wr[4j+r,k'] - sind*wi[4j+r,k']
        //   W_im = cosd*wi[4j+r,k'] + sind*wr[4j+r,k']
        int w  = blk - XP_BLOCKS;     // 0..143
        int gk = w >> 3;              // k'-group 0..17
        int j0 = (w & 7) * 64;        // j-block (0..448)
        int n0 = j0 * 4;              // source rows n0..n0+255 (<=2047)
        int kb = gk * 16;             // k' base (<=272; reads <=287 < 1025 OK)
        {
            int c  = threadIdx.x & 15;
            int rs = threadIdx.x >> 4;
#pragma unroll
            for (int it = 0; it < 16; ++it) {
                int row = rs + it * 16;
                long src = (long)(n0 + row) * KOUT + kb + c;
                sR[row][c] = wr[src];
                sI[row][c] = wi[src];
            }
        }
        __syncthreads();
        int q   = threadIdx.x >> 5;   // 0..7
        int jj0 = threadIdx.x & 31;
        int r   = q >> 1, im = q & 1;
#pragma unroll
        for (int u = 0; u < 16; ++u) {
            int kp = kb + u;
            float sd = 0.f, cd = 1.f;
            if (r > 0) {
                float a = (float)(r * kp) * PI_OVER_1024;
                sd = __sinf(a); cd = __cosf(a);
            }
#pragma unroll
            for (int jh = 0; jh < 2; ++jh) {
                int jj = jj0 + jh * 32;
                int nl = 4 * jj + r;
                float wrv = sR[nl][u], wiv = sI[nl][u];
                float val = im ? (cd * wiv + sd * wrv) : (cd * wrv - sd * wiv);
                if (kp > 256) val = 0.f;          // pad cols -> exact zero acc
                wbt[(long)(gk * 128 + q * 16 + u) * KD4 + j0 + jj] = f32_to_bf16(val);
            }
        }
    }
}

// ---------- main GEMM: radix-4, 128m x 256c, K=512, BK=64, 8 waves ----------
// Proven skeleton (8-granule XOR swizzle = 0 conflicts; band-per-XCD map;
// pure-__syncthreads loop). Per wave: 2 of 4 A-streams (sLo = (wave&1)*2).
// Epilogue: f32 acc -> LDS exchange -> per-lane 4-pt butterfly -> 4 outputs/k'.
__global__ __launch_bounds__(512, 2) void stft_gemm(const ushort_t* __restrict__ xs,
                                                    const ushort_t* __restrict__ wbt,
                                                    float* __restrict__ out) {
    union ShU {
        struct { ushort_t A[4 * 8192]; ushort_t B[16384]; } s;   // 96 KB staging
        float E[128 * 260];                                      // 130 KB exchange
    };
    __shared__ __align__(16) ShU sh;

    const int tid = threadIdx.x;
    const int f   = blockIdx.x;            // 0..719
    const int xcd = f & 7;
    const int ii  = f >> 3;                // 0..89
    const int mt  = xcd * BAND + (ii % BAND);
    const int nt  = ii / BAND;             // 0..8
    if (mt >= MT) return;                  // 9 dead wgs (whole block exits)
    const int m0  = mt * 128;
    const int c0  = nt * 256;              // packed col base (<=2048)

    // staging: slot s -> row=s>>3, phys granule=s&7, logical g=(s&7)^(row&7)
    int bcompA[2];                         // A source (per slot, stream/k added)
#pragma unroll
    for (int j = 0; j < 2; ++j) {
        int slot = j * 512 + tid;          // A: 128 rows x 8 granules
        int row  = slot >> 3;
        int g    = (slot & 7) ^ (row & 7);
        int m = m0 + row; if (m > MTOT - 1) m = MTOT - 1;   // clamp; stores guarded
        int b = m / TFR;
        int t = m - b * TFR;
        bcompA[j] = b * QLP + t * 128 + g * 8;   // frame hop = 128 per stream
    }
    int baseB[4];
#pragma unroll
    for (int j = 0; j < 4; ++j) {
        int slot = j * 512 + tid;          // B: 256 rows x 8 granules
        int row  = slot >> 3;
        int g    = (slot & 7) ^ (row & 7);
        baseB[j] = (c0 + row) * KD4 + g * 8;    // c0+row < 2304 always
    }

    const int wave = tid >> 6;             // 0..7
    const int lane = tid & 63;
    const int wm = (wave >> 2) * 64;       // 2 m-rows of waves
    const int wn = (wave & 3) * 64;        // 4 n-cols of waves
    const int lm = lane & 15;
    const int quad = lane >> 4;
    const int sLo = (wave & 1) * 2;        // this wave's A stream pair

    float4v acc[4][4];
#pragma unroll
    for (int mi = 0; mi < 4; ++mi)
#pragma unroll
        for (int ni = 0; ni < 4; ++ni)
            acc[mi][ni] = (float4v){0.f, 0.f, 0.f, 0.f};

#define STAGE(t_)                                                                 \
    do {                                                                          \
        int ko_ = (t_) * 64;                                                      \
        _Pragma("unroll")                                                         \
        for (int r_ = 0; r_ < 4; ++r_)                                            \
            _Pragma("unroll")                                                     \
            for (int j_ = 0; j_ < 2; ++j_)                                        \
                async_copy16(xs + r_ * SST + bcompA[j_] + ko_,                    \
                             (char*)sh.s.A + r_ * 16384 + (j_ * 512 + tid) * 16); \
        _Pragma("unroll")                                                         \
        for (int j_ = 0; j_ < 4; ++j_)                                            \
            async_copy16(wbt + baseB[j_] + ko_,                                   \
                         (char*)sh.s.B + (j_ * 512 + tid) * 16);                  \
    } while (0)

    STAGE(0);
    for (int t = 0; t < 8; ++t) {
        __syncthreads();                   // stage landed (vmcnt0+lgkm0+barrier)
        short8 a0[4], a1[4], b0[4], a0b[4], a1b[4], b1[4];
#pragma unroll
        for (int mi = 0; mi < 4; ++mi) {   // kk0 + kk1 A fragments (2 streams)
            int row = wm + mi * 16 + lm;
            int p0g = (quad) ^ (row & 7);
            int p1g = (4 + quad) ^ (row & 7);
            a0[mi]  = *(const short8*)&sh.s.A[sLo * 8192 + row * 64 + p0g * 8];
            a1[mi]  = *(const short8*)&sh.s.A[(sLo + 1) * 8192 + row * 64 + p0g * 8];
            a0b[mi] = *(const short8*)&sh.s.A[sLo * 8192 + row * 64 + p1g * 8];
            a1b[mi] = *(const short8*)&sh.s.A[(sLo + 1) * 8192 + row * 64 + p1g * 8];
        }
#pragma unroll
        for (int ni = 0; ni < 4; ++ni) {   // kk0 + kk1 B fragments
            int row = wn + ni * 16 + lm;
            int p0g = (quad) ^ (row & 7);
            int p1g = (4 + quad) ^ (row & 7);
            b0[ni] = *(const short8*)&sh.s.B[row * 64 + p0g * 8];
            b1[ni] = *(const short8*)&sh.s.B[row * 64 + p1g * 8];
        }
        __syncthreads();                   // all waves' reads in regs; LDS free
        if (t < 7) STAGE(t + 1);           // hidden under the 32-MFMA cluster

        __builtin_amdgcn_s_setprio(1);
#pragma unroll
        for (int mi = 0; mi < 4; ++mi)
#pragma unroll
            for (int ni = 0; ni < 4; ++ni)
                acc[mi][ni] = __builtin_amdgcn_mfma_f32_16x16x32_bf16(
                    (ni < 2) ? a0[mi] : a1[mi], b0[ni], acc[mi][ni], 0, 0, 0);
#pragma unroll
        for (int mi = 0; mi < 4; ++mi)
#pragma unroll
            for (int ni = 0; ni < 4; ++ni)
                acc[mi][ni] = __builtin_amdgcn_mfma_f32_16x16x32_bf16(
                    (ni < 2) ? a0b[mi] : a1b[mi], b1[ni], acc[mi][ni], 0, 0, 0);
        __builtin_amdgcn_s_setprio(0);
    }
#undef STAGE

    // ---- epilogue: LDS exchange (all streams per lane) + radix-4 butterfly ----
    // After t=7's 2nd __syncthreads all LDS reads are done and nothing is in
    // flight (t=7 staged nothing) -> safe to overwrite with the f32 exchange.
#pragma unroll
    for (int mi = 0; mi < 4; ++mi)
#pragma unroll
        for (int ni = 0; ni < 4; ++ni) {
            int cc = wn + ni * 16 + lm;
#pragma unroll
            for (int rg = 0; rg < 4; ++rg)
                sh.E[(wm + mi * 16 + quad * 4 + rg) * 260 + cc] = acc[mi][ni][rg];
        }
    __syncthreads();

    const int kl   = tid & 31;             // local k' (block covers 32)
    const int mseg = tid >> 5;             // 0..15 (8 m-rows each)
    const int kp   = nt * 32 + kl;
    if (kp <= 256) {
        float a1a = (float)kp * PI_OVER_1024;      // t_r = e^{-i r a}
        float s1 = __sinf(a1a), c1 = __cosf(a1a);
        float c2 = c1 * c1 - s1 * s1, s2 = 2.f * c1 * s1;
        float c3 = c2 * c1 - s2 * s1, s3 = s2 * c1 + c2 * s1;
        const int cb = (kl >> 4) * 128 + (kl & 15);
#pragma unroll
        for (int it = 0; it < 8; ++it) {
            int ml = mseg * 8 + it;
            int m  = m0 + ml;
            if (m < MTOT) {
                const float* Er = &sh.E[ml * 260 + cb];
                float F0r = Er[0],   F0i = Er[16];
                float e1r = Er[32],  e1i = Er[48];
                float e2r = Er[64],  e2i = Er[80];
                float e3r = Er[96],  e3i = Er[112];
                float F1r = c1 * e1r + s1 * e1i, F1i = c1 * e1i - s1 * e1r;
                float F2r = c2 * e2r + s2 * e2i, F2i = c2 * e2i - s2 * e2r;
                float F3r = c3 * e3r + s3 * e3i, F3i = c3 * e3i - s3 * e3r;
                float A0r = F0r + F1r + F2r + F3r, A0i = F0i + F1i + F2i + F3i;
                float A2r = F0r - F1r + F2r - F3r, A2i = F0i - F1i + F2i - F3i;
                float A1r = F0r + F1i - F2r - F3i, A1i = F0i - F1r - F2i + F3r;
                float A3r = F0r - F1i - F2r + F3i, A3i = F0i + F1r - F2i - F3r;
                long rb = (long)m * KOUT;
                out[rb + kp]                    = A0r;   // S[k']
                out[IMAG_OFF + rb + kp]         = A0i;
                out[rb + 512 + kp]              = A1r;   // S[512+k']
                out[IMAG_OFF + rb + 512 + kp]   = A1i;
                out[rb + 1024 - kp]             = A2r;   // conj(A2)
                out[IMAG_OFF + rb + 1024 - kp]  = -A2i;
                out[rb + 512 - kp]              = A3r;   // conj(A3)
                out[IMAG_OFF + rb + 512 - kp]   = -A3i;
            }
        }
    }
}

extern "C" void kernel_launch(void* const* d_in, const int* in_sizes, int n_in,
                              void* d_out, int out_size, void* d_ws, size_t ws_size,
                              hipStream_t stream) {
    const float* x  = (const float*)d_in[0];     // fp32 (16, 320000)
    const float* wr = (const float*)d_in[1];     // fp32 (2048, 1025)
    const float* wi = (const float*)d_in[2];     // fp32 (2048, 1025)
    float* out = (float*)d_out;                  // fp32, 2*16*626*1025

    ushort_t* xs  = (ushort_t*)d_ws;             // 4 streams x 1288192 bf16 = 10.3 MB
    ushort_t* wbt = xs + 4 * SST;                // 2304*512 bf16 = 2.36 MB

    prep<<<XP_BLOCKS + W4_BLOCKS, 256, 0, stream>>>(x, wr, wi, xs, wbt);
    stft_gemm<<<GEMM_GRID, 512, 0, stream>>>(xs, wbt, out);   // band-mapped
}

// Round 10
// 158.171 us; speedup vs baseline: 1.4167x; 1.0057x over previous
//
#include <hip/hip_runtime.h>
#include <math.h>

// ---------- problem constants ----------
#define BATCH   16
#define LIN     320000
#define LP      322048          // LIN + 2048 (reflect pad 1024 each side)
#define QLP     (LP/4)          // 80512 : 4-stream de-interleaved length per batch
#define SST     (BATCH*QLP)     // 1288192 : per-stream total elems
#define TFR     626             // frames per batch
#define MTOT    (BATCH*TFR)     // 10016
#define KD4     512             // radix-4 GEMM K (length-512 sub-DFTs)
#define KOUT    1025
#define IMAG_OFF ((long)MTOT*KOUT)   // 10266400

// radix-4 packed cols: C = g*128 + q*16 + u ; k' = g*16+u (0..287, valid<=256)
// q = 2r+im: (E0r,E0i,E1r,E1i,E2r,E2i,E3r,E3i), E_r = stream-r sub-DFT.
// S[k] = Sum_r e^{-i pi k r/1024} E_r[k mod 512];  E_r[512-k'] = conj(E_r[k'])
// -> F_r = t_r*E_r (t_r = e^{-i pi r k'/1024}), A_s = Sum_r (-i)^{rs} F_r:
//    S[k']=A0, S[512+k']=A1, S[1024-k']=conj(A2), S[512-k']=conj(A3)
#define BM  64                  // m-tile rows (was 128: shrunk for 2 blocks/CU)
#define MT  157                 // ceil(10016/64)
#define NT  9                   // k'-tiles (32 k' = 256 packed cols; 18 groups)
#define BAND 20                 // mt band per XCD (ceil(157/8))
#define GEMM_GRID (8*BAND*NT)   // 1440 (27 dead)

#define XP_BLOCKS   ((BATCH*LP)/2048)   // 2516 (8 elems/thread)
#define W4_BLOCKS   (18*8)              // 144: 18 k'-groups x 8 j-blocks

typedef __attribute__((ext_vector_type(8))) short short8;
typedef __attribute__((ext_vector_type(4))) float float4v;
typedef unsigned short ushort_t;

#define PI_OVER_1024 0.0030679615757712823f

static __device__ __forceinline__ ushort_t f32_to_bf16(float f) {
    union { float f; unsigned u; } un; un.f = f;
    unsigned r = un.u + 0x7fffu + ((un.u >> 16) & 1u);   // RNE
    return (ushort_t)(r >> 16);
}

static __device__ __forceinline__ void async_copy16(const void* g, void* l) {
    __builtin_amdgcn_global_load_lds(
        (const __attribute__((address_space(1))) void*)g,
        (__attribute__((address_space(3))) void*)l, 16, 0, 0);
}

// ---------- fused prep: 4-stream xp build | packed radix-4 weight build ----------
__global__ void prep(const float* __restrict__ x,
                     const float* __restrict__ wr,
                     const float* __restrict__ wi,
                     ushort_t* __restrict__ xs,
                     ushort_t* __restrict__ wbt) {
    __shared__ float sR[256][17];
    __shared__ float sI[256][17];
    const int blk = blockIdx.x;

    if (blk < XP_BLOCKS) {
        // reflect-pad fp32 x -> bf16, de-interleaved into 4 streams (n mod 4)
        int i0 = blk * 2048 + threadIdx.x * 8;   // multiple of 8; never spans batch
        int b  = i0 / LP;
        int p0 = i0 - b * LP;                    // multiple of 8
        float v[8];
        if (p0 >= 1024 && p0 + 8 <= 1024 + LIN) {        // interior fast path
            const float* src = x + b * LIN + (p0 - 1024);
            float4v u0 = *(const float4v*)src;
            float4v u1 = *(const float4v*)(src + 4);
#pragma unroll
            for (int e = 0; e < 4; ++e) { v[e] = u0[e]; v[4+e] = u1[e]; }
        } else {
#pragma unroll
            for (int e = 0; e < 8; ++e) {
                int i = i0 + e;
                int bb = i / LP;
                int j = (i - bb * LP) - 1024;
                if (j < 0) j = -j;
                else if (j >= LIN) j = 2 * LIN - 2 - j;
                v[e] = x[bb * LIN + j];
            }
        }
        int he = b * QLP + (p0 >> 2);            // even -> 4B aligned uint store
#pragma unroll
        for (int r = 0; r < 4; ++r) {
            unsigned lo = f32_to_bf16(v[r]);
            unsigned hi = f32_to_bf16(v[4 + r]);
            *(unsigned*)(xs + r * SST + he) = lo | (hi << 16);
        }
    } else {
        // packed radix-4 weight: row C = gk*128 + q*16 + u, cols j (K=512)
        // q=2r+im, delta = pi*r*k'/1024:
        //   W_re = cosd*wr[4j+r,k'] - sind*wi[4j+r,k']
        //   W_im = cosd*wi[4j+r,k'] + sind*wr[4j+r,k']
        int w  = blk - XP_BLOCKS;     // 0..143
        int gk = w >> 3;              // k'-group 0..17
        int j0 = (w & 7) * 64;        // j-block (0..448)
        int n0 = j0 * 4;              // source rows n0..n0+255 (<=2047)
        int kb = gk * 16;             // k' base (<=272; reads <=287 < 1025 OK)
        {
            int c  = threadIdx.x & 15;
            int rs = threadIdx.x >> 4;
#pragma unroll
            for (int it = 0; it < 16; ++it) {
                int row = rs + it * 16;
                long src = (long)(n0 + row) * KOUT + kb + c;
                sR[row][c] = wr[src];
                sI[row][c] = wi[src];
            }
        }
        __syncthreads();
        int q   = threadIdx.x >> 5;   // 0..7
        int jj0 = threadIdx.x & 31;
        int r   = q >> 1, im = q & 1;
#pragma unroll
        for (int u = 0; u < 16; ++u) {
            int kp = kb + u;
            float sd = 0.f, cd = 1.f;
            if (r > 0) {
                float a = (float)(r * kp) * PI_OVER_1024;
                sd = __sinf(a); cd = __cosf(a);
            }
#pragma unroll
            for (int jh = 0; jh < 2; ++jh) {
                int jj = jj0 + jh * 32;
                int nl = 4 * jj + r;
                float wrv = sR[nl][u], wiv = sI[nl][u];
                float val = im ? (cd * wiv + sd * wrv) : (cd * wrv - sd * wiv);
                if (kp > 256) val = 0.f;          // pad cols -> exact zero acc
                wbt[(long)(gk * 128 + q * 16 + u) * KD4 + j0 + jj] = f32_to_bf16(val);
            }
        }
    }
}

// ---------- main GEMM: radix-4, 64m x 256c, K=512, BK=64, 8 waves, 2 blk/CU ----
// R9's proven template (8-granule XOR swizzle, band-per-XCD map, pure-
// __syncthreads loop, LDS-exchange butterfly epilogue) at BM=64:
// staging 64 KB + E 66.6 KB union -> 2 blocks/CU -> cross-block TLP hides the
// per-tile vmcnt drain (the R5 regime; R9's 1 blk/CU was 70% pipe-idle).
// Per wave: ONE stream (r = wave&3), tile 64m x 32c, 12 ds_read / 16 MFMA.
__global__ __launch_bounds__(512, 4) void stft_gemm(const ushort_t* __restrict__ xs,
                                                    const ushort_t* __restrict__ wbt,
                                                    float* __restrict__ out) {
    union ShU {
        struct { ushort_t A[4 * 4096]; ushort_t B[16384]; } s;   // 64 KB staging
        float E[64 * 260];                                       // 66.6 KB exchange
    };
    __shared__ __align__(16) ShU sh;

    const int tid = threadIdx.x;
    const int f   = blockIdx.x;            // 0..1439
    const int xcd = f & 7;
    const int ii  = f >> 3;                // 0..179
    const int mt  = xcd * BAND + (ii % BAND);
    const int nt  = ii / BAND;             // 0..8
    if (mt >= MT) return;                  // 27 dead wgs (whole block exits)
    const int m0  = mt * BM;
    const int c0  = nt * 256;              // packed col base (<=2048)

    // staging: A slot (per stream) = tid -> row=tid>>3, g=(tid&7)^(row&7)
    int bcompA;                            // A source offset (stream/k added)
    {
        int row = tid >> 3;
        int g   = (tid & 7) ^ (row & 7);
        int m = m0 + row; if (m > MTOT - 1) m = MTOT - 1;   // clamp; stores guarded
        int b = m / TFR;
        int t = m - b * TFR;
        bcompA = b * QLP + t * 128 + g * 8;    // frame hop = 128 per stream
    }
    int baseB[4];
#pragma unroll
    for (int j = 0; j < 4; ++j) {
        int slot = j * 512 + tid;          // B: 256 rows x 8 granules
        int row  = slot >> 3;
        int g    = (slot & 7) ^ (row & 7);
        baseB[j] = (c0 + row) * KD4 + g * 8;    // c0+row < 2304 always
    }

    const int wave = tid >> 6;             // 0..7
    const int lane = tid & 63;
    const int grpw = wave >> 2;            // k'-group within block (0/1)
    const int rst  = wave & 3;             // this wave's stream
    const int wn   = grpw * 128 + rst * 32;// packed col base of wave (0..224)
    const int lm   = lane & 15;
    const int quad = lane >> 4;

    float4v acc[4][2];
#pragma unroll
    for (int mi = 0; mi < 4; ++mi)
#pragma unroll
        for (int ni = 0; ni < 2; ++ni)
            acc[mi][ni] = (float4v){0.f, 0.f, 0.f, 0.f};

#define STAGE(t_)                                                                 \
    do {                                                                          \
        int ko_ = (t_) * 64;                                                      \
        _Pragma("unroll")                                                         \
        for (int r_ = 0; r_ < 4; ++r_)                                            \
            async_copy16(xs + r_ * SST + bcompA + ko_,                            \
                         (char*)sh.s.A + r_ * 8192 + tid * 16);                   \
        _Pragma("unroll")                                                         \
        for (int j_ = 0; j_ < 4; ++j_)                                            \
            async_copy16(wbt + baseB[j_] + ko_,                                   \
                         (char*)sh.s.B + (j_ * 512 + tid) * 16);                  \
    } while (0)

    STAGE(0);
    for (int t = 0; t < 8; ++t) {
        __syncthreads();                   // stage landed (vmcnt0+lgkm0+barrier)
        short8 a[4][2], b[2][2];
#pragma unroll
        for (int mi = 0; mi < 4; ++mi) {   // A: stream rst, kk0+kk1
            int row = mi * 16 + lm;        // 0..63
#pragma unroll
            for (int kk = 0; kk < 2; ++kk) {
                int pg = (kk * 4 + quad) ^ (row & 7);
                a[mi][kk] = *(const short8*)&sh.s.A[rst * 4096 + row * 64 + pg * 8];
            }
        }
#pragma unroll
        for (int ni = 0; ni < 2; ++ni) {   // B: wave's 32-col slice, kk0+kk1
            int row = wn + ni * 16 + lm;   // 0..255
#pragma unroll
            for (int kk = 0; kk < 2; ++kk) {
                int pg = (kk * 4 + quad) ^ (row & 7);
                b[ni][kk] = *(const short8*)&sh.s.B[row * 64 + pg * 8];
            }
        }
        __syncthreads();                   // all waves' reads in regs; LDS free
        if (t < 7) STAGE(t + 1);           // hidden under the MFMA cluster

        __builtin_amdgcn_s_setprio(1);
#pragma unroll
        for (int kk = 0; kk < 2; ++kk)
#pragma unroll
            for (int mi = 0; mi < 4; ++mi)
#pragma unroll
                for (int ni = 0; ni < 2; ++ni)
                    acc[mi][ni] = __builtin_amdgcn_mfma_f32_16x16x32_bf16(
                        a[mi][kk], b[ni][kk], acc[mi][ni], 0, 0, 0);
        __builtin_amdgcn_s_setprio(0);
    }
#undef STAGE

    // ---- epilogue: LDS exchange (all streams per lane) + radix-4 butterfly ----
    // After t=7's 2nd __syncthreads all LDS reads are done and nothing is in
    // flight (t=7 staged nothing) -> safe to overwrite with the f32 exchange.
#pragma unroll
    for (int mi = 0; mi < 4; ++mi)
#pragma unroll
        for (int ni = 0; ni < 2; ++ni) {
            int cc = wn + ni * 16 + lm;
#pragma unroll
            for (int rg = 0; rg < 4; ++rg)
                sh.E[(mi * 16 + quad * 4 + rg) * 260 + cc] = acc[mi][ni][rg];
        }
    __syncthreads();

    const int kl   = tid & 31;             // local k' (block covers 32)
    const int mseg = tid >> 5;             // 0..15 (4 m-rows each)
    const int kp   = nt * 32 + kl;
    if (kp <= 256) {
        float a1a = (float)kp * PI_OVER_1024;      // t_r = e^{-i r a}
        float s1 = __sinf(a1a), c1 = __cosf(a1a);
        float c2 = c1 * c1 - s1 * s1, s2 = 2.f * c1 * s1;
        float c3 = c2 * c1 - s2 * s1, s3 = s2 * c1 + c2 * s1;
        const int cb = (kl >> 4) * 128 + (kl & 15);
#pragma unroll
        for (int it = 0; it < 4; ++it) {
            int ml = mseg * 4 + it;
            int m  = m0 + ml;
            if (m < MTOT) {
                const float* Er = &sh.E[ml * 260 + cb];
                float F0r = Er[0],   F0i = Er[16];
                float e1r = Er[32],  e1i = Er[48];
                float e2r = Er[64],  e2i = Er[80];
                float e3r = Er[96],  e3i = Er[112];
                float F1r = c1 * e1r + s1 * e1i, F1i = c1 * e1i - s1 * e1r;
                float F2r = c2 * e2r + s2 * e2i, F2i = c2 * e2i - s2 * e2r;
                float F3r = c3 * e3r + s3 * e3i, F3i = c3 * e3i - s3 * e3r;
                float A0r = F0r + F1r + F2r + F3r, A0i = F0i + F1i + F2i + F3i;
                float A2r = F0r - F1r + F2r - F3r, A2i = F0i - F1i + F2i - F3i;
                float A1r = F0r + F1i - F2r - F3i, A1i = F0i - F1r - F2i + F3r;
                float A3r = F0r - F1i - F2r + F3i, A3i = F0i + F1r - F2i - F3r;
                long rb = (long)m * KOUT;
                out[rb + kp]                    = A0r;   // S[k']
                out[IMAG_OFF + rb + kp]         = A0i;
                out[rb + 512 + kp]              = A1r;   // S[512+k']
                out[IMAG_OFF + rb + 512 + kp]   = A1i;
                out[rb + 1024 - kp]             = A2r;   // conj(A2)
                out[IMAG_OFF + rb + 1024 - kp]  = -A2i;
                out[rb + 512 - kp]              = A3r;   // conj(A3)
                out[IMAG_OFF + rb + 512 - kp]   = -A3i;
            }
        }
    }
}

extern "C" void kernel_launch(void* const* d_in, const int* in_sizes, int n_in,
                              void* d_out, int out_size, void* d_ws, size_t ws_size,
                              hipStream_t stream) {
    const float* x  = (const float*)d_in[0];     // fp32 (16, 320000)
    const float* wr = (const float*)d_in[1];     // fp32 (2048, 1025)
    const float* wi = (const float*)d_in[2];     // fp32 (2048, 1025)
    float* out = (float*)d_out;                  // fp32, 2*16*626*1025

    ushort_t* xs  = (ushort_t*)d_ws;             // 4 streams x 1288192 bf16 = 10.3 MB
    ushort_t* wbt = xs + 4 * SST;                // 2304*512 bf16 = 2.36 MB

    prep<<<XP_BLOCKS + W4_BLOCKS, 256, 0, stream>>>(x, wr, wi, xs, wbt);
    stft_gemm<<<GEMM_GRID, 512, 0, stream>>>(xs, wbt, out);   // band-mapped
}